// Round 11
// baseline (150.169 us; speedup 1.0000x reference)
//
#include <hip/hip_runtime.h>
#include <hip/hip_bf16.h>

#define NB 4
#define CCH 256
#define NN 4096
#define KSPLIT 8
#define MRANGE (NN / KSPLIT)     // 512 m per wave-task
#define MTILE 32
#define NTILES (MRANGE / MTILE)  // 16

// sqrt(log2(e)/16): fold softmax scale + exp2 conversion into x symmetrically
#define SQRTK 0.30028060f

typedef __attribute__((ext_vector_type(8))) short short8;
typedef __attribute__((ext_vector_type(16))) float f32x16;
typedef __attribute__((ext_vector_type(4))) int i32x4;

__device__ inline ushort f2bf(float f) {
    uint u = __float_as_uint(f);
    uint r = (u + 0x7fffu + ((u >> 16) & 1u)) >> 16;
    return (ushort)r;
}

__device__ inline float dev_exp2(float x) {
#if __has_builtin(__builtin_amdgcn_exp2f)
    return __builtin_amdgcn_exp2f(x);
#else
    return exp2f(x);
#endif
}

// ---------------- Kernel E: W fp32 -> bf16 ----------------
__global__ void wconv_k(const float* __restrict__ W, ushort* __restrict__ Wb) {
    int i = blockIdx.x * 256 + threadIdx.x;  // 16384 float4
    float4 v = reinterpret_cast<const float4*>(W)[i];
    ushort4 r;
    r.x = f2bf(v.x); r.y = f2bf(v.y); r.z = f2bf(v.z); r.w = f2bf(v.w);
    reinterpret_cast<ushort4*>(Wb)[i] = r;
}

// ---------------- Kernel B': fused transpose+linear, 512 wgs (2 wg/CU)
// Per wg: 32 n-rows x full C. Transpose inp [B][C][N] via f32 LDS tile
// (4 c-blocks), build bf16 [n][c] tile, then MFMA GEMM vs Wb (L2-hot).
__global__ __launch_bounds__(256) void fusedlin_k(const float* __restrict__ inp,
                                                  const ushort* __restrict__ Wb,
                                                  const float* __restrict__ bias,
                                                  ushort* __restrict__ xs) {
    int wg = blockIdx.x;                 // 512: b(2) | nt(7)
    int b = wg >> 7, nt = wg & 127;
    int t = threadIdx.x, l = t & 63, w = t >> 6;
    __shared__ float ftile[64 * 33];
    __shared__ ushort xtile[32][260];    // row stride 520B: 2-way conflicts only

    for (int cblk = 0; cblk < 4; cblk++) {
        const float* src = inp + ((size_t)(b * CCH + cblk * 64)) * NN + nt * 32;
#pragma unroll
        for (int p = 0; p < 2; p++) {
            int ci = p * 256 + t;        // 0..511
            int c = ci >> 3, n4 = ci & 7;
            float4 v = *reinterpret_cast<const float4*>(src + (size_t)c * NN + n4 * 4);
            float* d = &ftile[c * 33 + n4 * 4];
            d[0] = v.x; d[1] = v.y; d[2] = v.z; d[3] = v.w;
        }
        __syncthreads();
        {
            int n = t >> 3, cc = t & 7;  // 32 n x 8 cc = 256
            ushort tmp[8];
#pragma unroll
            for (int j = 0; j < 8; j++) tmp[j] = f2bf(ftile[(cc * 8 + j) * 33 + n]);
            uint4 o;
            o.x = (uint)tmp[0] | ((uint)tmp[1] << 16);
            o.y = (uint)tmp[2] | ((uint)tmp[3] << 16);
            o.z = (uint)tmp[4] | ((uint)tmp[5] << 16);
            o.w = (uint)tmp[6] | ((uint)tmp[7] << 16);
            *reinterpret_cast<uint4*>(&xtile[n][cblk * 64 + cc * 8]) = o;
        }
        __syncthreads();
    }

    int obase = w * 64;
    const ushort* wrow = Wb + ((size_t)(obase + (l & 31))) * CCH + ((l >> 5) * 8);
    f32x16 acc[2];
#pragma unroll
    for (int os = 0; os < 2; os++)
#pragma unroll
        for (int r = 0; r < 16; r++) acc[os][r] = 0.f;

    const char* arow = (const char*)&xtile[l & 31][0] + (l >> 5) * 16;
#pragma unroll
    for (int ch = 0; ch < 16; ch++) {
        short8 a = *reinterpret_cast<const short8*>(arow + ch * 32);
#pragma unroll
        for (int os = 0; os < 2; os++) {
            short8 bb = *reinterpret_cast<const short8*>(wrow + (size_t)os * 32 * CCH + ch * 16);
            acc[os] = __builtin_amdgcn_mfma_f32_32x32x16_bf16(a, bb, acc[os], 0, 0, 0);
        }
    }
#pragma unroll
    for (int os = 0; os < 2; os++) {
        int oc = obase + os * 32 + (l & 31);
        float bv = bias[oc];
#pragma unroll
        for (int r = 0; r < 16; r++) {
            int row = (r & 3) + 8 * (r >> 2) + 4 * (l >> 5);
            float v = (acc[os][r] + bv) * SQRTK;
            xs[((size_t)(b * NN + nt * 32 + row)) * CCH + oc] = f2bf(v);
        }
    }
}

// ---------------- Kernel C: BARRIER-FREE flash attention
// Evidence R1-R10: per-tile __syncthreads+vmcnt(0) drain ~0.4-1us dominates
// (MfmaUtil 33% on a 15us MFMA floor / 44us wall). Fix: no LDS K-staging at
// all — each wave reads K-fragments directly from global xs (row mb+(l&31),
// 16B chunk; 16KB tile is L2/L3-resident, sectors L1-reused 4x within the
// ch-loop). Waves fully independent: wave w owns ks = kspair*4+w. One sync
// after the V'-build, then ZERO barriers. LDS 16.5KB/wg + ~115 VGPR ->
// 4 wg/CU = 16 drifting waves/CU for latency hiding.
// Swapped QK^T (q on lanes, m in regs); V' = [fx,fy,1,0] pre-permuted
// (bits 2<->3 of m&15) so P packs in reg order: 8 cvt_pk, no shuffles.
__global__ __launch_bounds__(256, 4) void attn_k(const ushort* __restrict__ xs,
                                                 const float* __restrict__ flow,
                                                 float* __restrict__ part) {
    int wg = blockIdx.x;                 // 1024: b(2) | qt(7) | kspair(1)
    int b = wg >> 8;
    int qt = (wg >> 1) & 127;
    int kp = wg & 1;
    int t = threadIdx.x, l = t & 63, w = t >> 6;   // w = 0..3
    const ushort* xb = xs + (size_t)b * NN * CCH;
    int qbase = qt * 32;
    int ks = kp * 4 + w;
    int mstart = ks * MRANGE;            // global m start for THIS wave

    // V' for the wg's 2048-m range, perm-ordered: fx|fy|1|0
    __shared__ alignas(16) ushort vlds[4][2048 + 8];
    {
        int m0 = t * 8;                  // 256 threads x 8 m = 2048
        int gm = kp * 2048 + m0;
        float4 fx4a = *reinterpret_cast<const float4*>(flow + (size_t)b * 2 * NN + gm);
        float4 fx4b = *reinterpret_cast<const float4*>(flow + (size_t)b * 2 * NN + gm + 4);
        float4 fy4a = *reinterpret_cast<const float4*>(flow + (size_t)b * 2 * NN + NN + gm);
        float4 fy4b = *reinterpret_cast<const float4*>(flow + (size_t)b * 2 * NN + NN + gm + 4);
        float fxv[8] = {fx4a.x, fx4a.y, fx4a.z, fx4a.w, fx4b.x, fx4b.y, fx4b.z, fx4b.w};
        float fyv[8] = {fy4a.x, fy4a.y, fy4a.z, fy4a.w, fy4b.x, fy4b.y, fy4b.z, fy4b.w};
#pragma unroll
        for (int i = 0; i < 8; i++) {
            int m = m0 + i, ml = m & 15;
            int pos = (m & ~15) | (ml & 3) | ((ml & 4) << 1) | ((ml & 8) >> 1);
            vlds[0][pos] = f2bf(fxv[i]);
            vlds[1][pos] = f2bf(fyv[i]);
            vlds[2][pos] = 0x3F80;       // bf16 1.0
            vlds[3][pos] = 0;
        }
    }

    // Q fragments: 32 q-rows x 256 c per wave
    short8 qf[16];
    const ushort* qrow = xb + ((size_t)(qbase + (l & 31))) * CCH + (l >> 5) * 8;
#pragma unroll
    for (int ch = 0; ch < 16; ch++)
        qf[ch] = *reinterpret_cast<const short8*>(qrow + ch * 16);

    __syncthreads();                     // vlds ready; last sync in the kernel

    f32x16 pv;                           // persistent: cols {X,Y,S,0...}
#pragma unroll
    for (int r = 0; r < 16; r++) pv[r] = 0.f;

    int c_sel = (l & 31) < 3 ? (l & 31) : 3;
    const ushort* kbase = xb + ((size_t)(mstart + (l & 31))) * CCH + (l >> 5) * 8;
    int vbase_off = kp ? -2048 : 0;      // vlds is indexed by m - kp*2048

    for (int tile = 0; tile < NTILES; tile++) {
        f32x16 S;
#pragma unroll
        for (int r = 0; r < 16; r++) S[r] = 0.f;
        const ushort* kt = kbase + (size_t)(tile * MTILE) * CCH;
#pragma unroll
        for (int ch = 0; ch < 16; ch++) {
            short8 kf = *reinterpret_cast<const short8*>(kt + ch * 16);
            // swapped: A=K (rows=m), B=Q (cols=q)
            S = __builtin_amdgcn_mfma_f32_32x32x16_bf16(kf, qf[ch], S, 0, 0, 0);
        }
#pragma unroll
        for (int r = 0; r < 16; r++) S[r] = dev_exp2(S[r]);
        uint wd[8];
#pragma unroll
        for (int p = 0; p < 8; p++) {
            asm("v_cvt_pk_bf16_f32 %0, %1, %2" : "=v"(wd[p]) : "v"(S[2 * p]), "v"(S[2 * p + 1]));
        }
        i32x4 lo4 = {(int)wd[0], (int)wd[1], (int)wd[2], (int)wd[3]};
        i32x4 hi4 = {(int)wd[4], (int)wd[5], (int)wd[6], (int)wd[7]};
        short8 pa0 = __builtin_bit_cast(short8, lo4);
        short8 pa1 = __builtin_bit_cast(short8, hi4);
        int mloc = mstart + tile * MTILE + vbase_off;   // local to vlds
        const ushort* vb = &vlds[c_sel][mloc + (l >> 5) * 8];
        short8 v0 = *reinterpret_cast<const short8*>(vb);
        short8 v1 = *reinterpret_cast<const short8*>(vb + 16);
        pv = __builtin_amdgcn_mfma_f32_32x32x16_bf16(pa0, v0, pv, 0, 0, 0);
        pv = __builtin_amdgcn_mfma_f32_32x32x16_bf16(pa1, v1, pv, 0, 0, 0);
    }

    // epilogue: lane col 0 holds X, 1 holds Y, 2 holds S (16 q each)
    int c = l & 31;
    if (c < 3) {
        float* pb = part + ((size_t)(b * KSPLIT + ks)) * 3 * NN;
        int off = ((c + 1) % 3) * NN;    // c2->S@0, c0->X@NN, c1->Y@2NN
#pragma unroll
        for (int r = 0; r < 16; r++) {
            int row = (r & 3) + 8 * (r >> 2) + 4 * (l >> 5);
            pb[off + qbase + row] = pv[r];
        }
    }
}

// ---------------- Kernel D: combine k-split partials, divide, write output
__global__ void finalize_k(const float* __restrict__ part, float* __restrict__ out) {
    int i = blockIdx.x * 256 + threadIdx.x;  // 16384
    int b = i >> 12, n = i & 4095;
    float s = 0.f, x = 0.f, y = 0.f;
#pragma unroll
    for (int ks = 0; ks < KSPLIT; ks++) {
        const float* p = part + ((size_t)(b * KSPLIT + ks)) * 3 * NN;
        s += p[n];
        x += p[NN + n];
        y += p[2 * NN + n];
    }
    out[(size_t)b * 2 * NN + n] = x / s;
    out[(size_t)b * 2 * NN + NN + n] = y / s;
}

extern "C" void kernel_launch(void* const* d_in, const int* in_sizes, int n_in,
                              void* d_out, int out_size, void* d_ws, size_t ws_size,
                              hipStream_t stream) {
    const float* inp  = (const float*)d_in[0];
    // d_in[1] = inter_mask: unused by the reference
    const float* flow = (const float*)d_in[2];
    const float* W    = (const float*)d_in[3];
    const float* bias = (const float*)d_in[4];
    float* out = (float*)d_out;

    char* ws = (char*)d_ws;
    ushort* xs   = (ushort*)(ws);                  // 8 MB  x_scaled bf16 [B][N][C]
    float*  part = (float*)(ws + 8388608);         // 1.57MB partials [B][KS][3][N]
    ushort* Wb   = (ushort*)(ws + 16777216);       // 128KB W bf16 [C][C]

    wconv_k<<<64, 256, 0, stream>>>(W, Wb);
    fusedlin_k<<<512, 256, 0, stream>>>(inp, Wb, bias, xs);
    attn_k<<<1024, 256, 0, stream>>>(xs, flow, part);
    finalize_k<<<64, 256, 0, stream>>>(part, out);
}

// Round 12
// 67.620 us; speedup vs baseline: 2.2208x; 2.2208x over previous
//
#include <hip/hip_runtime.h>
#include <hip/hip_bf16.h>

#define NB 4
#define CCH 256
#define NN 4096
#define QT 128
#define KSPLIT 4
#define MRANGE (NN / KSPLIT)
#define MTILE 64
#define NTILES (MRANGE / MTILE)
#define VPAD 8

// sqrt(log2(e)/16): fold softmax scale + exp2 conversion into x symmetrically
#define SQRTK 0.30028060f

typedef __attribute__((ext_vector_type(8))) short short8;
typedef __attribute__((ext_vector_type(16))) float f32x16;
typedef __attribute__((ext_vector_type(4))) int i32x4;

__device__ inline ushort f2bf(float f) {
    uint u = __float_as_uint(f);
    uint r = (u + 0x7fffu + ((u >> 16) & 1u)) >> 16;
    return (ushort)r;
}

__device__ inline float dev_exp2(float x) {
#if __has_builtin(__builtin_amdgcn_exp2f)
    return __builtin_amdgcn_exp2f(x);
#else
    return exp2f(x);
#endif
}

__device__ inline void gl_lds16(const void* g, void* l) {
    __builtin_amdgcn_global_load_lds(
        (const __attribute__((address_space(1))) unsigned int*)g,
        (__attribute__((address_space(3))) unsigned int*)l, 16, 0, 0);
}

// ---------------- Kernel E: W fp32 -> bf16 ----------------
__global__ void wconv_k(const float* __restrict__ W, ushort* __restrict__ Wb) {
    int i = blockIdx.x * 256 + threadIdx.x;  // 16384 float4
    float4 v = reinterpret_cast<const float4*>(W)[i];
    ushort4 r;
    r.x = f2bf(v.x); r.y = f2bf(v.y); r.z = f2bf(v.z); r.w = f2bf(v.w);
    reinterpret_cast<ushort4*>(Wb)[i] = r;
}

// ---------------- Kernel B': fused transpose+linear, 512 wgs (2 wg/CU)
__global__ __launch_bounds__(256) void fusedlin_k(const float* __restrict__ inp,
                                                  const ushort* __restrict__ Wb,
                                                  const float* __restrict__ bias,
                                                  ushort* __restrict__ xs) {
    int wg = blockIdx.x;                 // 512: b(2) | nt(7)
    int b = wg >> 7, nt = wg & 127;
    int t = threadIdx.x, l = t & 63, w = t >> 6;
    __shared__ float ftile[64 * 33];
    __shared__ ushort xtile[32][260];    // row stride 520B: 2-way conflicts only

    for (int cblk = 0; cblk < 4; cblk++) {
        const float* src = inp + ((size_t)(b * CCH + cblk * 64)) * NN + nt * 32;
#pragma unroll
        for (int p = 0; p < 2; p++) {
            int ci = p * 256 + t;        // 0..511
            int c = ci >> 3, n4 = ci & 7;
            float4 v = *reinterpret_cast<const float4*>(src + (size_t)c * NN + n4 * 4);
            float* d = &ftile[c * 33 + n4 * 4];
            d[0] = v.x; d[1] = v.y; d[2] = v.z; d[3] = v.w;
        }
        __syncthreads();
        {
            int n = t >> 3, cc = t & 7;  // 32 n x 8 cc = 256
            ushort tmp[8];
#pragma unroll
            for (int j = 0; j < 8; j++) tmp[j] = f2bf(ftile[(cc * 8 + j) * 33 + n]);
            uint4 o;
            o.x = (uint)tmp[0] | ((uint)tmp[1] << 16);
            o.y = (uint)tmp[2] | ((uint)tmp[3] << 16);
            o.z = (uint)tmp[4] | ((uint)tmp[5] << 16);
            o.w = (uint)tmp[6] | ((uint)tmp[7] << 16);
            *reinterpret_cast<uint4*>(&xtile[n][cblk * 64 + cc * 8]) = o;
        }
        __syncthreads();
    }

    int obase = w * 64;
    const ushort* wrow = Wb + ((size_t)(obase + (l & 31))) * CCH + ((l >> 5) * 8);
    f32x16 acc[2];
#pragma unroll
    for (int os = 0; os < 2; os++)
#pragma unroll
        for (int r = 0; r < 16; r++) acc[os][r] = 0.f;

    const char* arow = (const char*)&xtile[l & 31][0] + (l >> 5) * 16;
#pragma unroll
    for (int ch = 0; ch < 16; ch++) {
        short8 a = *reinterpret_cast<const short8*>(arow + ch * 32);
#pragma unroll
        for (int os = 0; os < 2; os++) {
            short8 bb = *reinterpret_cast<const short8*>(wrow + (size_t)os * 32 * CCH + ch * 16);
            acc[os] = __builtin_amdgcn_mfma_f32_32x32x16_bf16(a, bb, acc[os], 0, 0, 0);
        }
    }
#pragma unroll
    for (int os = 0; os < 2; os++) {
        int oc = obase + os * 32 + (l & 31);
        float bv = bias[oc];
#pragma unroll
        for (int r = 0; r < 16; r++) {
            int row = (r & 3) + 8 * (r >> 2) + 4 * (l >> 5);
            float v = (acc[os][r] + bv) * SQRTK;
            xs[((size_t)(b * NN + nt * 32 + row)) * CCH + oc] = f2bf(v);
        }
    }
}

// ---------------- Kernel C: flash attention, R9 shell + INTERLEAVED S-CHAINS
// R9's QK inner loop was one 16-deep serial MFMA accumulate: each
// S=mfma(...,S) pays full result latency, not the 8-cyc issue rate, and at
// 2 waves/SIMD the matrix pipe idles on the chain (R10: halving LDS reads
// changed nothing -> LDS wasn't critical; the chain was). Here both 32-row
// m-subtiles of the tile run as INDEPENDENT chains S0/S1 interleaved in one
// ch-loop (2x MFMA ILP, +16 VGPR). Everything else is the proven R9 shell:
// cooperative dbuf staging + __syncthreads, swapped QK^T, V'=[fx,fy,1,0]
// pre-permuted (bits 2<->3 of m&15), PV+denominator via MFMA, no tile-loop
// unroll, (256,2) so the compiler has a 256-VGPR budget (no squeeze-spill).
__global__ __launch_bounds__(256, 2) void attn_k(const ushort* __restrict__ xs,
                                                 const float* __restrict__ flow,
                                                 float* __restrict__ part) {
    int wg = blockIdx.x;                 // 512: b(2) | qt(5) | ks(2)
    int b = wg >> 7;
    int qt = (wg >> 2) & 31;
    int ks = wg & 3;
    int t = threadIdx.x, l = t & 63, w = t >> 6;   // w = 0..3
    const ushort* xb = xs + (size_t)b * NN * CCH;
    int qbase = qt * QT + w * 32;
    int mstart = ks * MRANGE;

    __shared__ ushort kt[2][MTILE * 256];        // 2 x 32KB K-tiles
    __shared__ ushort vlds[4][MRANGE + VPAD];    // perm-ordered V': fx|fy|1|0

    // build V' (one-time): thread t handles m = t*4..t*4+3 of this wg's slice
    {
        int m0 = t * 4;
        float4 fx4 = *reinterpret_cast<const float4*>(flow + (size_t)b * 2 * NN + mstart + m0);
        float4 fy4 = *reinterpret_cast<const float4*>(flow + (size_t)b * 2 * NN + NN + mstart + m0);
        float fxv[4] = {fx4.x, fx4.y, fx4.z, fx4.w};
        float fyv[4] = {fy4.x, fy4.y, fy4.z, fy4.w};
#pragma unroll
        for (int i = 0; i < 4; i++) {
            int m = m0 + i, ml = m & 15;
            int pos = (m & ~15) | (ml & 3) | ((ml & 4) << 1) | ((ml & 8) >> 1);
            vlds[0][pos] = f2bf(fxv[i]);
            vlds[1][pos] = f2bf(fyv[i]);
            vlds[2][pos] = 0x3F80;       // bf16 1.0
            vlds[3][pos] = 0;
        }
    }

    // Q fragments in registers: 32 q-rows x 256 c per wave
    short8 qf[16];
    const ushort* qrow = xb + ((size_t)(qbase + (l & 31))) * CCH + (l >> 5) * 8;
#pragma unroll
    for (int ch = 0; ch < 16; ch++)
        qf[ch] = *reinterpret_cast<const short8*>(qrow + ch * 16);

    f32x16 pv;                           // persistent: cols {X,Y,S,0...}
#pragma unroll
    for (int r = 0; r < 16; r++) pv[r] = 0.f;

    // staging: 32 chunks of 1KB across 4 waves; source XOR-swizzled (16 slots)
    auto stage = [&](int buf, int tile) {
        int mb = mstart + tile * MTILE;
        const char* src = (const char*)(xb + (size_t)mb * CCH);
#pragma unroll
        for (int p = 0; p < 8; p++) {
            int chunk = w * 8 + p;
            int lin = chunk * 1024 + l * 16;
            int row = lin >> 9;
            int cb = lin & 511;
            int gsw = cb ^ ((row & 15) << 4);
            gl_lds16(src + (size_t)row * 512 + gsw, &kt[buf][chunk * 512]);
        }
    };

    int c_sel = (l & 31) < 3 ? (l & 31) : 3;
    stage(0, 0);
    __syncthreads();
    int cur = 0;
    for (int tile = 0; tile < NTILES; tile++) {
        if (tile + 1 < NTILES) stage(cur ^ 1, tile + 1);
        f32x16 S0, S1;
#pragma unroll
        for (int r = 0; r < 16; r++) { S0[r] = 0.f; S1[r] = 0.f; }
        const char* base0 = (const char*)&kt[cur][(l & 31) * 256];
        const char* base1 = (const char*)&kt[cur][(32 + (l & 31)) * 256];
        int swz = (l & 15) << 4;
#pragma unroll
        for (int ch = 0; ch < 16; ch++) {
            int cbyte = (ch * 32 + ((l >> 5) * 16)) ^ swz;
            short8 kf0 = *reinterpret_cast<const short8*>(base0 + cbyte);
            short8 kf1 = *reinterpret_cast<const short8*>(base1 + cbyte);
            // two independent accumulation chains on the same qf[ch]
            S0 = __builtin_amdgcn_mfma_f32_32x32x16_bf16(kf0, qf[ch], S0, 0, 0, 0);
            S1 = __builtin_amdgcn_mfma_f32_32x32x16_bf16(kf1, qf[ch], S1, 0, 0, 0);
        }
#pragma unroll
        for (int r = 0; r < 16; r++) { S0[r] = dev_exp2(S0[r]); S1[r] = dev_exp2(S1[r]); }
        uint wa[8], wb2[8];
#pragma unroll
        for (int p = 0; p < 8; p++) {
            asm("v_cvt_pk_bf16_f32 %0, %1, %2" : "=v"(wa[p]) : "v"(S0[2 * p]), "v"(S0[2 * p + 1]));
            asm("v_cvt_pk_bf16_f32 %0, %1, %2" : "=v"(wb2[p]) : "v"(S1[2 * p]), "v"(S1[2 * p + 1]));
        }
        i32x4 a0 = {(int)wa[0], (int)wa[1], (int)wa[2], (int)wa[3]};
        i32x4 a1 = {(int)wa[4], (int)wa[5], (int)wa[6], (int)wa[7]};
        i32x4 b0 = {(int)wb2[0], (int)wb2[1], (int)wb2[2], (int)wb2[3]};
        i32x4 b1 = {(int)wb2[4], (int)wb2[5], (int)wb2[6], (int)wb2[7]};
        short8 pa00 = __builtin_bit_cast(short8, a0);
        short8 pa01 = __builtin_bit_cast(short8, a1);
        short8 pa10 = __builtin_bit_cast(short8, b0);
        short8 pa11 = __builtin_bit_cast(short8, b1);
        int mloc0 = tile * MTILE;
        int mloc1 = tile * MTILE + 32;
        const ushort* vb0 = &vlds[c_sel][mloc0 + (l >> 5) * 8];
        const ushort* vb1 = &vlds[c_sel][mloc1 + (l >> 5) * 8];
        short8 v00 = *reinterpret_cast<const short8*>(vb0);
        short8 v01 = *reinterpret_cast<const short8*>(vb0 + 16);
        short8 v10 = *reinterpret_cast<const short8*>(vb1);
        short8 v11 = *reinterpret_cast<const short8*>(vb1 + 16);
        pv = __builtin_amdgcn_mfma_f32_32x32x16_bf16(pa00, v00, pv, 0, 0, 0);
        pv = __builtin_amdgcn_mfma_f32_32x32x16_bf16(pa01, v01, pv, 0, 0, 0);
        pv = __builtin_amdgcn_mfma_f32_32x32x16_bf16(pa10, v10, pv, 0, 0, 0);
        pv = __builtin_amdgcn_mfma_f32_32x32x16_bf16(pa11, v11, pv, 0, 0, 0);
        __syncthreads();
        cur ^= 1;
    }

    // epilogue: lane col 0 holds X, 1 holds Y, 2 holds S (16 q each)
    int c = l & 31;
    if (c < 3) {
        float* pb = part + ((size_t)(b * KSPLIT + ks)) * 3 * NN;
        int off = ((c + 1) % 3) * NN;    // c2->S@0, c0->X@NN, c1->Y@2NN
#pragma unroll
        for (int r = 0; r < 16; r++) {
            int row = (r & 3) + 8 * (r >> 2) + 4 * (l >> 5);
            pb[off + qbase + row] = pv[r];
        }
    }
}

// ---------------- Kernel D: combine k-split partials, divide, write output
__global__ void finalize_k(const float* __restrict__ part, float* __restrict__ out) {
    int i = blockIdx.x * 256 + threadIdx.x;  // 16384
    int b = i >> 12, n = i & 4095;
    float s = 0.f, x = 0.f, y = 0.f;
#pragma unroll
    for (int ks = 0; ks < KSPLIT; ks++) {
        const float* p = part + ((size_t)(b * KSPLIT + ks)) * 3 * NN;
        s += p[n];
        x += p[NN + n];
        y += p[2 * NN + n];
    }
    out[(size_t)b * 2 * NN + n] = x / s;
    out[(size_t)b * 2 * NN + NN + n] = y / s;
}

extern "C" void kernel_launch(void* const* d_in, const int* in_sizes, int n_in,
                              void* d_out, int out_size, void* d_ws, size_t ws_size,
                              hipStream_t stream) {
    const float* inp  = (const float*)d_in[0];
    // d_in[1] = inter_mask: unused by the reference
    const float* flow = (const float*)d_in[2];
    const float* W    = (const float*)d_in[3];
    const float* bias = (const float*)d_in[4];
    float* out = (float*)d_out;

    char* ws = (char*)d_ws;
    ushort* xs   = (ushort*)(ws);                  // 8 MB  x_scaled bf16 [B][N][C]
    float*  part = (float*)(ws + 8388608);         // 768KB partials [B][KS][3][N]
    ushort* Wb   = (ushort*)(ws + 16777216);       // 128KB W bf16 [C][C]

    wconv_k<<<64, 256, 0, stream>>>(W, Wb);
    fusedlin_k<<<512, 256, 0, stream>>>(inp, Wb, bias, xs);
    attn_k<<<512, 256, 0, stream>>>(xs, flow, part);
    finalize_k<<<64, 256, 0, stream>>>(part, out);
}

// Round 13
// 63.212 us; speedup vs baseline: 2.3756x; 1.0697x over previous
//
#include <hip/hip_runtime.h>
#include <hip/hip_bf16.h>

#define NB 4
#define CCH 256
#define NN 4096
#define QT 128
#define KSPLIT 4
#define MRANGE (NN / KSPLIT)
#define MTILE 64
#define NTILES (MRANGE / MTILE)
#define VPAD 8

// sqrt(log2(e)/16): fold softmax scale + exp2 conversion into x symmetrically
#define SQRTK 0.30028060f

typedef __attribute__((ext_vector_type(8))) short short8;
typedef __attribute__((ext_vector_type(16))) float f32x16;
typedef __attribute__((ext_vector_type(4))) int i32x4;

__device__ inline ushort f2bf(float f) {
    uint u = __float_as_uint(f);
    uint r = (u + 0x7fffu + ((u >> 16) & 1u)) >> 16;
    return (ushort)r;
}

__device__ inline float dev_exp2(float x) {
#if __has_builtin(__builtin_amdgcn_exp2f)
    return __builtin_amdgcn_exp2f(x);
#else
    return exp2f(x);
#endif
}

__device__ inline void gl_lds16(const void* g, void* l) {
    __builtin_amdgcn_global_load_lds(
        (const __attribute__((address_space(1))) unsigned int*)g,
        (__attribute__((address_space(3))) unsigned int*)l, 16, 0, 0);
}

// ---------------- Kernel A: transpose inp [B][C][N] fp32 -> inpT [B][N][C] bf16
//                  + tail blocks (>=1024): W fp32 -> bf16 conversion
__global__ __launch_bounds__(256) void transp_k(const float* __restrict__ inp,
                                                ushort* __restrict__ inpT,
                                                const float* __restrict__ W,
                                                ushort* __restrict__ Wb) {
    if (blockIdx.x >= 1024) {            // 64 tail wgs: convert W (16384 float4)
        int i = (blockIdx.x - 1024) * 256 + threadIdx.x;
        float4 v = reinterpret_cast<const float4*>(W)[i];
        ushort4 r;
        r.x = f2bf(v.x); r.y = f2bf(v.y); r.z = f2bf(v.z); r.w = f2bf(v.w);
        reinterpret_cast<ushort4*>(Wb)[i] = r;
        return;
    }
    int wg = blockIdx.x;                 // 1024: b(2) | cblk(2) | nblk(6)
    int nblk = wg & 63, cblk = (wg >> 6) & 3, b = wg >> 8;
    __shared__ float tile[64 * 67];
    int t = threadIdx.x;
    const float* src = inp + ((size_t)(b * CCH + cblk * 64)) * NN + nblk * 64;
#pragma unroll
    for (int p = 0; p < 4; p++) {
        int ci = p * 256 + t;            // 0..1023
        int c = ci >> 4, n4 = ci & 15;
        float4 v = *reinterpret_cast<const float4*>(src + (size_t)c * NN + n4 * 4);
        float* d = &tile[c * 67 + n4 * 4];
        d[0] = v.x; d[1] = v.y; d[2] = v.z; d[3] = v.w;
    }
    __syncthreads();
    ushort* dst = inpT + ((size_t)(b * NN + nblk * 64)) * CCH + cblk * 64;
#pragma unroll
    for (int p = 0; p < 2; p++) {
        int u = p * 256 + t;             // 0..511
        int n = u >> 3, cc = u & 7;
        ushort tmp[8];
#pragma unroll
        for (int j = 0; j < 8; j++) tmp[j] = f2bf(tile[(cc * 8 + j) * 67 + n]);
        uint4 o;
        o.x = (uint)tmp[0] | ((uint)tmp[1] << 16);
        o.y = (uint)tmp[2] | ((uint)tmp[3] << 16);
        o.z = (uint)tmp[4] | ((uint)tmp[5] << 16);
        o.w = (uint)tmp[6] | ((uint)tmp[7] << 16);
        *reinterpret_cast<uint4*>(dst + (size_t)n * CCH + cc * 8) = o;
    }
}

// ---------------- Kernel B: xs[b][n][o] = bf16( (inpT[b][n][:] . Wb[o][:] + bias[o]) * SQRTK )
__global__ __launch_bounds__(256) void linear_k(const ushort* __restrict__ inpT,
                                                const ushort* __restrict__ Wb,
                                                const float* __restrict__ bias,
                                                ushort* __restrict__ xs) {
    int wg = blockIdx.x;                 // 256: b(2) | ntile(6)
    int b = wg >> 6, nt = wg & 63;
    int t = threadIdx.x, l = t & 63, w = t >> 6;
    int nbase = nt * 64 + (w & 1) * 32;
    int obase = (w >> 1) * 128;
    const ushort* arow = inpT + ((size_t)(b * NN + nbase + (l & 31))) * CCH + ((l >> 5) * 8);
    const ushort* wrow = Wb + ((size_t)(obase + (l & 31))) * CCH + ((l >> 5) * 8);
    f32x16 acc[4];
#pragma unroll
    for (int os = 0; os < 4; os++)
#pragma unroll
        for (int r = 0; r < 16; r++) acc[os][r] = 0.f;

#pragma unroll
    for (int ch = 0; ch < 16; ch++) {
        short8 a = *reinterpret_cast<const short8*>(arow + ch * 16);
#pragma unroll
        for (int os = 0; os < 4; os++) {
            short8 bb = *reinterpret_cast<const short8*>(wrow + (size_t)os * 32 * CCH + ch * 16);
            acc[os] = __builtin_amdgcn_mfma_f32_32x32x16_bf16(a, bb, acc[os], 0, 0, 0);
        }
    }
#pragma unroll
    for (int os = 0; os < 4; os++) {
        int oc = obase + os * 32 + (l & 31);
        float bv = bias[oc];
#pragma unroll
        for (int r = 0; r < 16; r++) {
            int row = (r & 3) + 8 * (r >> 2) + 4 * (l >> 5);
            float v = (acc[os][r] + bv) * SQRTK;
            xs[((size_t)(b * NN + nt * 64 + (w & 1) * 32 + row)) * CCH + oc] = f2bf(v);
        }
    }
}

// ---------------- Kernel C: flash attention, T15 epilogue pipelining
// R12 evidence: no pipe >52% busy, MFMA/exp/PV phases serialize within each
// wave (2 waves/SIMD can't fill the gaps). Fix: per iteration compute
// QK(t+1) -> Sn FIRST, then epilogue(t) on Sp — exp2/cvt_pk/PV of tile t
// are register-only, independent of QK(t+1)'s chains, so they fill the
// MFMA shadow (separate pipes). PV split pvA/pvB halves its serial chain.
// Shell otherwise R9-proven: dbuf + __syncthreads (drains vmcnt before
// s_barrier -> stage(t+2) lands one tile early, no stall), swapped QK^T,
// V'=[fx,fy,1,0] pre-permuted (bits 2<->3 of m&15), PV+denominator via
// MFMA. ~190 regs: (256,2) = 256-VGPR budget, no squeeze (R2/R4/R6/R11:
// squeezed bounds => spill/remat disaster). unroll 2 ping-pongs S sets.
__global__ __launch_bounds__(256, 2) void attn_k(const ushort* __restrict__ xs,
                                                 const float* __restrict__ flow,
                                                 float* __restrict__ part) {
    int wg = blockIdx.x;                 // 512: b(2) | qt(5) | ks(2)
    int b = wg >> 7;
    int qt = (wg >> 2) & 31;
    int ks = wg & 3;
    int t = threadIdx.x, l = t & 63, w = t >> 6;   // w = 0..3
    const ushort* xb = xs + (size_t)b * NN * CCH;
    int qbase = qt * QT + w * 32;
    int mstart = ks * MRANGE;

    __shared__ ushort kt[2][MTILE * 256];        // 2 x 32KB K-tiles
    __shared__ ushort vlds[4][MRANGE + VPAD];    // perm-ordered V': fx|fy|1|0

    // build V' (one-time): thread t handles m = t*4..t*4+3 of this wg's slice
    {
        int m0 = t * 4;
        float4 fx4 = *reinterpret_cast<const float4*>(flow + (size_t)b * 2 * NN + mstart + m0);
        float4 fy4 = *reinterpret_cast<const float4*>(flow + (size_t)b * 2 * NN + NN + mstart + m0);
        float fxv[4] = {fx4.x, fx4.y, fx4.z, fx4.w};
        float fyv[4] = {fy4.x, fy4.y, fy4.z, fy4.w};
#pragma unroll
        for (int i = 0; i < 4; i++) {
            int m = m0 + i, ml = m & 15;
            int pos = (m & ~15) | (ml & 3) | ((ml & 4) << 1) | ((ml & 8) >> 1);
            vlds[0][pos] = f2bf(fxv[i]);
            vlds[1][pos] = f2bf(fyv[i]);
            vlds[2][pos] = 0x3F80;       // bf16 1.0
            vlds[3][pos] = 0;
        }
    }

    // Q fragments in registers: 32 q-rows x 256 c per wave
    short8 qf[16];
    const ushort* qrow = xb + ((size_t)(qbase + (l & 31))) * CCH + (l >> 5) * 8;
#pragma unroll
    for (int ch = 0; ch < 16; ch++)
        qf[ch] = *reinterpret_cast<const short8*>(qrow + ch * 16);

    f32x16 pvA, pvB;                     // persistent: cols {X,Y,S,0...}
#pragma unroll
    for (int r = 0; r < 16; r++) { pvA[r] = 0.f; pvB[r] = 0.f; }

    // staging: 32 chunks of 1KB across 4 waves; source XOR-swizzled (16 slots)
    auto stage = [&](int buf, int tile) {
        int mb = mstart + tile * MTILE;
        const char* src = (const char*)(xb + (size_t)mb * CCH);
#pragma unroll
        for (int p = 0; p < 8; p++) {
            int chunk = w * 8 + p;
            int lin = chunk * 1024 + l * 16;
            int row = lin >> 9;
            int cb = lin & 511;
            int gsw = cb ^ ((row & 15) << 4);
            gl_lds16(src + (size_t)row * 512 + gsw, &kt[buf][chunk * 512]);
        }
    };

    // QK of one 64-m tile: two independent 16-deep chains (m-halves)
    auto qk = [&](int buf, f32x16& S0, f32x16& S1) {
#pragma unroll
        for (int r = 0; r < 16; r++) { S0[r] = 0.f; S1[r] = 0.f; }
        const char* base0 = (const char*)&kt[buf][(l & 31) * 256];
        const char* base1 = base0 + 32 * 512;
        int swz = (l & 15) << 4;
#pragma unroll
        for (int ch = 0; ch < 16; ch++) {
            int cbyte = (ch * 32 + ((l >> 5) * 16)) ^ swz;
            short8 kf0 = *reinterpret_cast<const short8*>(base0 + cbyte);
            short8 kf1 = *reinterpret_cast<const short8*>(base1 + cbyte);
            S0 = __builtin_amdgcn_mfma_f32_32x32x16_bf16(kf0, qf[ch], S0, 0, 0, 0);
            S1 = __builtin_amdgcn_mfma_f32_32x32x16_bf16(kf1, qf[ch], S1, 0, 0, 0);
        }
    };

    int c_sel = (l & 31) < 3 ? (l & 31) : 3;

    stage(0, 0);
    __syncthreads();
    f32x16 Sp0, Sp1;
    qk(0, Sp0, Sp1);                     // QK(0)
    stage(1, 1);

#pragma unroll 2
    for (int tile = 0; tile < NTILES; tile++) {
        __syncthreads();                 // buf(t+1) staged & landed; buf(t) consumed
        f32x16 Sn0, Sn1;
        if (tile + 1 < NTILES) qk((tile + 1) & 1, Sn0, Sn1);
        if (tile + 2 < NTILES) stage(tile & 1, tile + 2);

        // ---- epilogue(t) on Sp: register-only, fills QK(t+1)'s MFMA shadow
#pragma unroll
        for (int r = 0; r < 16; r++) { Sp0[r] = dev_exp2(Sp0[r]); Sp1[r] = dev_exp2(Sp1[r]); }
        uint wa[8], wb2[8];
#pragma unroll
        for (int p = 0; p < 8; p++) {
            asm("v_cvt_pk_bf16_f32 %0, %1, %2" : "=v"(wa[p]) : "v"(Sp0[2 * p]), "v"(Sp0[2 * p + 1]));
            asm("v_cvt_pk_bf16_f32 %0, %1, %2" : "=v"(wb2[p]) : "v"(Sp1[2 * p]), "v"(Sp1[2 * p + 1]));
        }
        i32x4 a0 = {(int)wa[0], (int)wa[1], (int)wa[2], (int)wa[3]};
        i32x4 a1 = {(int)wa[4], (int)wa[5], (int)wa[6], (int)wa[7]};
        i32x4 b0 = {(int)wb2[0], (int)wb2[1], (int)wb2[2], (int)wb2[3]};
        i32x4 b1 = {(int)wb2[4], (int)wb2[5], (int)wb2[6], (int)wb2[7]};
        short8 pa00 = __builtin_bit_cast(short8, a0);
        short8 pa01 = __builtin_bit_cast(short8, a1);
        short8 pa10 = __builtin_bit_cast(short8, b0);
        short8 pa11 = __builtin_bit_cast(short8, b1);
        const ushort* vb0 = &vlds[c_sel][tile * MTILE + (l >> 5) * 8];
        const ushort* vb1 = vb0 + 32;
        short8 v00 = *reinterpret_cast<const short8*>(vb0);
        short8 v01 = *reinterpret_cast<const short8*>(vb0 + 16);
        short8 v10 = *reinterpret_cast<const short8*>(vb1);
        short8 v11 = *reinterpret_cast<const short8*>(vb1 + 16);
        pvA = __builtin_amdgcn_mfma_f32_32x32x16_bf16(pa00, v00, pvA, 0, 0, 0);
        pvB = __builtin_amdgcn_mfma_f32_32x32x16_bf16(pa10, v10, pvB, 0, 0, 0);
        pvA = __builtin_amdgcn_mfma_f32_32x32x16_bf16(pa01, v01, pvA, 0, 0, 0);
        pvB = __builtin_amdgcn_mfma_f32_32x32x16_bf16(pa11, v11, pvB, 0, 0, 0);

        Sp0 = Sn0; Sp1 = Sn1;
    }

    // epilogue: lane col 0 holds X, 1 holds Y, 2 holds S (16 q each)
    int c = l & 31;
    if (c < 3) {
        float* pb = part + ((size_t)(b * KSPLIT + ks)) * 3 * NN;
        int off = ((c + 1) % 3) * NN;    // c2->S@0, c0->X@NN, c1->Y@2NN
#pragma unroll
        for (int r = 0; r < 16; r++) {
            int row = (r & 3) + 8 * (r >> 2) + 4 * (l >> 5);
            pb[off + qbase + row] = pvA[r] + pvB[r];
        }
    }
}

// ---------------- Kernel D: combine k-split partials, divide, write output
__global__ void finalize_k(const float* __restrict__ part, float* __restrict__ out) {
    int i = blockIdx.x * 256 + threadIdx.x;  // 16384
    int b = i >> 12, n = i & 4095;
    float s = 0.f, x = 0.f, y = 0.f;
#pragma unroll
    for (int ks = 0; ks < KSPLIT; ks++) {
        const float* p = part + ((size_t)(b * KSPLIT + ks)) * 3 * NN;
        s += p[n];
        x += p[NN + n];
        y += p[2 * NN + n];
    }
    out[(size_t)b * 2 * NN + n] = x / s;
    out[(size_t)b * 2 * NN + NN + n] = y / s;
}

extern "C" void kernel_launch(void* const* d_in, const int* in_sizes, int n_in,
                              void* d_out, int out_size, void* d_ws, size_t ws_size,
                              hipStream_t stream) {
    const float* inp  = (const float*)d_in[0];
    // d_in[1] = inter_mask: unused by the reference
    const float* flow = (const float*)d_in[2];
    const float* W    = (const float*)d_in[3];
    const float* bias = (const float*)d_in[4];
    float* out = (float*)d_out;

    char* ws = (char*)d_ws;
    ushort* xs   = (ushort*)(ws);                  // 8 MB  x_scaled bf16 [B][N][C]
    ushort* inpT = (ushort*)(ws + 8388608);        // 8 MB  inp^T bf16   [B][N][C]
    ushort* Wb   = (ushort*)(ws + 16777216);       // 128KB W bf16       [C][C]
    // part overlaps inpT's region: inpT is dead after linear_k, part is
    // written by attn_k afterwards; deterministic each replay.
    float*  part = (float*)(ws + 8388608);         // 768KB partials [B][KS][3][N]

    transp_k<<<1088, 256, 0, stream>>>(inp, inpT, W, Wb);
    linear_k<<<256, 256, 0, stream>>>(inpT, Wb, bias, xs);
    attn_k<<<512, 256, 0, stream>>>(xs, flow, part);
    finalize_k<<<64, 256, 0, stream>>>(part, out);
}